// Round 6
// baseline (1225.870 us; speedup 1.0000x reference)
//
#include <hip/hip_runtime.h>
#include <hip/hip_bf16.h>
#include <math.h>

#define COUT 64
#define EPS  1e-5f

typedef __hip_bfloat16 bf16;
typedef short  short8  __attribute__((ext_vector_type(8)));
typedef short  short4v __attribute__((ext_vector_type(4)));
typedef float  floatx4 __attribute__((ext_vector_type(4)));

__device__ __forceinline__ short bf16_bits(float f) {
    union { __hip_bfloat16 h; short s; } u;
    u.h = __float2bfloat16(f);
    return u.s;
}
__device__ __forceinline__ float bits_to_f32(short s) {
    union { __hip_bfloat16 h; short s; } u;
    u.s = s;
    return __bfloat162float(u.h);
}

// ---------------- geometry ----------------
#define H1_PLANE    (134*262)
#define H2_PLANE    (132*260)
#define NPOS1 (16*130*258)
#define NPOS2 (16*132*260)
#define CW1_N (130*258)     /* 33540 */
#define CW2_N (132*260)     /* 34320 */

// block counts for fused prep (exact, to avoid off-by-one)
#define CW1_BLK ((CW1_N + 255)/256)   /* 132 */
#define CW2_BLK ((CW2_N + 255)/256)   /* 135 */
#define PK1_BLK (9*1024/256)          /* 36 */
#define PK2_BLK (18*1024/256)         /* 72 */

// ---------------- fused prep: zero stats + cw1 + cw2 + pack1 + pack2 --------
__device__ __forceinline__ void cw_body(const float* __restrict__ ah, const float* __restrict__ aw,
                                        float* __restrict__ cw, int Lh, int Lw, int idx) {
    int n = Lh*Lw;
    if (idx >= n) return;
    int i = idx / Lw, j = idx - i*Lw;
    float v0 = ah[0*Lh+i] + aw[0*Lw+j];
    float v1 = ah[1*Lh+i] + aw[1*Lw+j];
    float v2 = ah[2*Lh+i] + aw[2*Lw+j];
    float v3 = ah[3*Lh+i] + aw[3*Lw+j];
    float m = fmaxf(fmaxf(v0,v1), fmaxf(v2,v3));
    v0 = __expf(v0-m); v1 = __expf(v1-m); v2 = __expf(v2-m); v3 = __expf(v3-m);
    float inv = 1.f/(v0+v1+v2+v3);
    cw[0*n+idx] = v0*inv; cw[1*n+idx] = v1*inv;
    cw[2*n+idx] = v2*inv; cw[3*n+idx] = v3*inv;
}

// Apk[((s*16+t)*64+l)*8+j] = A[m=t*16+(l&15)][k=s*32+(l>>4)*8+j], k=tap*CIN+ci
template<int CIN_, int NSLICES>
__device__ __forceinline__ void pack_body(const float* __restrict__ w, short* __restrict__ Apk, int gid) {
    if (gid >= NSLICES*1024) return;
    int l = gid & 63, t = (gid >> 6) & 15, s = gid >> 10;
    int m = t*16 + (l & 15);
    int r = m >> 6, co = m & 63;
    int kbase = s*32 + ((l >> 4) << 3);
    short8 v;
    #pragma unroll
    for (int j = 0; j < 8; ++j) {
        int k = kbase + j;
        int tap = k / CIN_, ci = k % CIN_;
        v[j] = bf16_bits(w[(((size_t)(r*COUT + co))*CIN_ + ci)*9 + tap]);
    }
    *reinterpret_cast<short8*>(Apk + (size_t)gid*8) = v;
}

__global__ void prep_kernel(const float* __restrict__ a1h, const float* __restrict__ a1w,
                            const float* __restrict__ a2h, const float* __restrict__ a2w,
                            const float* __restrict__ w1, const float* __restrict__ w2,
                            float* __restrict__ stats, float* __restrict__ cw1,
                            float* __restrict__ cw2, short* __restrict__ Apk1,
                            short* __restrict__ Apk2) {
    int bx = blockIdx.x;
    if (bx == 0) {
        stats[threadIdx.x] = 0.f; stats[threadIdx.x + 256] = 0.f;
    } else if (bx < 1 + CW1_BLK) {
        cw_body(a1h, a1w, cw1, 130, 258, (bx-1)*256 + threadIdx.x);
    } else if (bx < 1 + CW1_BLK + CW2_BLK) {
        cw_body(a2h, a2w, cw2, 132, 260, (bx-(1+CW1_BLK))*256 + threadIdx.x);
    } else if (bx < 1 + CW1_BLK + CW2_BLK + PK1_BLK) {
        pack_body<32, 9>(w1, Apk1, (bx-(1+CW1_BLK+CW2_BLK))*256 + threadIdx.x);
    } else {
        pack_body<64,18>(w2, Apk2, (bx-(1+CW1_BLK+CW2_BLK+PK1_BLK))*256 + threadIdx.x);
    }
}
#define PREP_BLOCKS (1 + CW1_BLK + CW2_BLK + PK1_BLK + PK2_BLK)  /* 376 */

// ---------------- fused: zero h1pad + build xpad -----------------------------
#define ZBLK 2048
__global__ void zero_xpad_kernel(uint4* __restrict__ h1p, long n4,
                                 const float* __restrict__ x, short* __restrict__ xp) {
    if (blockIdx.x < ZBLK) {
        for (long i = (long)blockIdx.x*256 + threadIdx.x; i < n4; i += (long)ZBLK*256)
            h1p[i] = make_uint4(0,0,0,0);
    } else {
        int row = blockIdx.x - ZBLK;          // b*132 + ih
        int b = row / 132, ih = row - b*132;
        int ci = threadIdx.x & 31, iw0 = threadIdx.x >> 5;
        for (int iw = iw0; iw < 260; iw += 8) {
            float v = 0.f;
            if (ih >= 2 && ih < 130 && iw >= 2 && iw < 258)
                v = x[(((size_t)b*32 + ci)*128 + (ih-2))*256 + (iw-2)];
            xp[((size_t)row*260 + iw)*32 + ci] = bf16_bits(v);
        }
    }
}

// ---------------- LDS-staged MFMA implicit-GEMM LRLC conv --------------------
// Block = 4 waves. Output tile: 4 rows x 32 cols (N=128), M=256 (4 rank x 64 co).
// Input patch 6 rows x 34 cols x CIN staged to LDS once; K-loop barrier-free.
// wave w owns m-tiles {i*4+w}: frag-row i == rank i, co in [w*16, w*16+16).
template<int CIN_, int NSLICES>
__launch_bounds__(256, 2)
__global__ void lrlc_conv(const short* __restrict__ Bpl, const short* __restrict__ Apk,
                          const float* __restrict__ cw, const float* __restrict__ bias,
                          short* __restrict__ Out, float* __restrict__ sum, float* __restrict__ sq,
                          int Hin, int Win, int Hout, int Wout,
                          int outW, int outPlane, int outPad) {
    constexpr int GSH = (CIN_ == 64) ? 3 : 2;      // 16B groups per col = CIN_/8
    constexpr int GPC = 1 << GSH;
    constexpr int TILE_SLOTS = 6*34*GPC;
    __shared__ short tile[TILE_SLOTS*8];
    __shared__ float cwS[512];

    const int tid  = threadIdx.x;
    const int w    = tid >> 6, l = tid & 63;
    const int quad = l >> 4, l15 = l & 15;
    const int b    = blockIdx.z;
    const int ow0  = blockIdx.x * 32;
    const int oh0  = blockIdx.y * 4;

    // combining weights for this tile (clamped; invalid n masked at store)
    for (int t = tid; t < 512; t += 256) {
        int r = t >> 7, n = t & 127;
        int oh = min(oh0 + (n >> 5), Hout-1);
        int ow = min(ow0 + (n & 31), Wout-1);
        cwS[t] = cw[((size_t)r*Hout + oh)*Wout + ow];
    }
    // stage input patch: rows oh0..oh0+5, cols ow0..ow0+33 (clamped)
    const short* Bb = Bpl + (size_t)b*Hin*Win*CIN_;
    for (int slot = tid; slot < TILE_SLOTS; slot += 256) {
        int g  = slot & (GPC-1); int cu = slot >> GSH;
        int rr = cu / 34, cc = cu - rr*34;
        int ih = min(oh0 + rr, Hin-1);
        int ic = min(ow0 + cc, Win-1);
        *reinterpret_cast<short8*>(&tile[slot*8]) =
            *reinterpret_cast<const short8*>(Bb + ((size_t)ih*Win + ic)*CIN_ + g*8);
    }
    __syncthreads();

    // per-j LDS base (position part); tap adds a compile-time constant
    int base0[8];
    #pragma unroll
    for (int j = 0; j < 8; ++j) {
        int n = j*16 + l15;
        base0[j] = (((n >> 5)*34 + (n & 31)) << GSH) + quad;
    }

    floatx4 acc[4][8];
    #pragma unroll
    for (int i = 0; i < 4; ++i)
        #pragma unroll
        for (int j = 0; j < 8; ++j)
            acc[i][j] = (floatx4){0.f,0.f,0.f,0.f};

    #pragma unroll
    for (int s = 0; s < NSLICES; ++s) {
        const int tap = (CIN_ == 32) ? s : (s >> 1);
        const int g0  = (CIN_ == 32) ? 0 : ((s & 1) << 2);
        const int koff = (((tap/3)*34 + (tap%3)) << GSH) + g0;
        short8 afr[4], bfr[8];
        #pragma unroll
        for (int i = 0; i < 4; ++i)
            afr[i] = *reinterpret_cast<const short8*>(
                Apk + (size_t)s*8192 + i*2048 + w*512 + l*8);
        #pragma unroll
        for (int j = 0; j < 8; ++j)
            bfr[j] = *reinterpret_cast<const short8*>(&tile[(base0[j] + koff)*8]);
        #pragma unroll
        for (int i = 0; i < 4; ++i)
            #pragma unroll
            for (int j = 0; j < 8; ++j)
                acc[i][j] = __builtin_amdgcn_mfma_f32_16x16x32_bf16(afr[i], bfr[j], acc[i][j], 0, 0, 0);
    }

    // epilogue: rank-combine, +bias, store bf16x4, fused BN stats (fp32)
    const int co_base = w*16 + quad*4;
    float bs[4];
    #pragma unroll
    for (int rg = 0; rg < 4; ++rg) bs[rg] = bias[co_base + rg];
    float st[4] = {0.f,0.f,0.f,0.f}, st2[4] = {0.f,0.f,0.f,0.f};
    #pragma unroll
    for (int j = 0; j < 8; ++j) {
        int n  = j*16 + l15;
        int oh = oh0 + (n >> 5), ow = ow0 + (n & 31);
        bool valid = (oh < Hout) && (ow < Wout);
        float c0 = cwS[n], c1 = cwS[128+n], c2 = cwS[256+n], c3 = cwS[384+n];
        short4v pk;
        #pragma unroll
        for (int rg = 0; rg < 4; ++rg) {
            float v = acc[0][j][rg]*c0 + acc[1][j][rg]*c1
                    + acc[2][j][rg]*c2 + acc[3][j][rg]*c3 + bs[rg];
            if (valid) { st[rg] += v; st2[rg] = fmaf(v, v, st2[rg]); }
            pk[rg] = bf16_bits(v);
        }
        if (valid) {
            size_t op = ((size_t)b*outPlane + (size_t)(oh + outPad)*outW + (ow + outPad))*(size_t)COUT + co_base;
            *reinterpret_cast<short4v*>(Out + op) = pk;
        }
    }
    #pragma unroll
    for (int m = 1; m < 16; m <<= 1) {
        #pragma unroll
        for (int rg = 0; rg < 4; ++rg) {
            st[rg]  += __shfl_xor(st[rg],  m, 16);
            st2[rg] += __shfl_xor(st2[rg], m, 16);
        }
    }
    if (l15 == 0) {
        #pragma unroll
        for (int rg = 0; rg < 4; ++rg) {
            atomicAdd(&sum[co_base+rg], st[rg]);
            atomicAdd(&sq[co_base+rg],  st2[rg]);
        }
    }
}

__global__ void finalize_kernel(const float* __restrict__ sum, const float* __restrict__ sumsq,
                                const float* __restrict__ g, const float* __restrict__ be,
                                float* __restrict__ A, float* __restrict__ Bc, float cnt) {
    int c = threadIdx.x;
    if (c >= COUT) return;
    float mean = sum[c]/cnt;
    float var  = sumsq[c]/cnt - mean*mean;
    float inv  = rsqrtf(var + EPS);
    float a = g[c]*inv;
    A[c]  = a;
    Bc[c] = fmaf(-mean, a, be[c]);
}

// row-based in-place BN+ReLU on h1pad interior; grid 16*130, block 256
__global__ void bnrelu_rows(short* __restrict__ h, const float* __restrict__ A,
                            const float* __restrict__ Bc) {
    __shared__ float sA[64], sB[64];
    if (threadIdx.x < 64) { sA[threadIdx.x] = A[threadIdx.x]; sB[threadIdx.x] = Bc[threadIdx.x]; }
    __syncthreads();
    int row = blockIdx.x;                 // b*130 + oh
    int b = row / 130, oh = row - b*130;
    short* base = h + ((size_t)(b*134 + oh + 2)*262 + 2)*64;
    const int nvec = 258*64/8;            // 2064
    for (int it = threadIdx.x; it < nvec; it += 256) {
        short8 d = *reinterpret_cast<short8*>(base + it*8);
        int c0 = (it*8) & 63;
        #pragma unroll
        for (int q = 0; q < 8; ++q) {
            float v = bits_to_f32(d[q]);
            int c = c0 + q;
            v = fmaxf(fmaf(v, sA[c], sB[c]), 0.f);
            d[q] = bf16_bits(v);
        }
        *reinterpret_cast<short8*>(base + it*8) = d;
    }
}

// fused BN2+ReLU+3x3/3 maxpool: h2 NHWC -> out fp32 NCHW [16,64,44,86]
__global__ void maxpool_rows(const short* __restrict__ h2, const float* __restrict__ A,
                             const float* __restrict__ Bc, float* __restrict__ out) {
    __shared__ float sA[64], sB[64];
    if (threadIdx.x < 64) { sA[threadIdx.x] = A[threadIdx.x]; sB[threadIdx.x] = Bc[threadIdx.x]; }
    __syncthreads();
    int row = blockIdx.x;                 // b*44 + ph
    int b = row / 44, ph = row - b*44;
    for (int item = threadIdx.x; item < 86*16; item += 256) {
        int cg = item & 15, pw = item >> 4;
        float m[4] = {0.f,0.f,0.f,0.f};
        #pragma unroll
        for (int i = 0; i < 3; ++i) {
            const short* rp = h2 + ((size_t)(b*132 + ph*3 + i)*260 + pw*3)*64 + cg*4;
            #pragma unroll
            for (int j = 0; j < 3; ++j) {
                short4v d = *reinterpret_cast<const short4v*>(rp + j*64);
                #pragma unroll
                for (int q = 0; q < 4; ++q) {
                    int c = cg*4 + q;
                    float v = fmaf(bits_to_f32(d[q]), sA[c], sB[c]);
                    m[q] = fmaxf(m[q], v);
                }
            }
        }
        #pragma unroll
        for (int q = 0; q < 4; ++q)
            out[((size_t)(b*64 + cg*4 + q)*44 + ph)*86 + pw] = m[q];
    }
}

extern "C" void kernel_launch(void* const* d_in, const int* in_sizes, int n_in,
                              void* d_out, int out_size, void* d_ws, size_t ws_size,
                              hipStream_t stream) {
    const float* x   = (const float*)d_in[0];
    const float* w1  = (const float*)d_in[1];
    const float* b1  = (const float*)d_in[2];
    const float* a1h = (const float*)d_in[3];
    const float* a1w = (const float*)d_in[4];
    const float* g1  = (const float*)d_in[5];
    const float* be1 = (const float*)d_in[6];
    const float* w2  = (const float*)d_in[7];
    const float* b2  = (const float*)d_in[8];
    const float* a2h = (const float*)d_in[9];
    const float* a2w = (const float*)d_in[10];
    const float* g2  = (const float*)d_in[11];
    const float* be2 = (const float*)d_in[12];
    float* out = (float*)d_out;

    char* ws = (char*)d_ws;
    float* stats = (float*)ws;                    // 512 floats
    float* sum1 = stats;       float* sq1 = stats + 64;
    float* A1   = stats + 128; float* Bc1 = stats + 192;
    float* sum2 = stats + 256; float* sq2 = stats + 320;
    float* A2   = stats + 384; float* Bc2 = stats + 448;
    float* cw1 = (float*)(ws + 2048);             // 4*CW1_N floats
    float* cw2 = cw1 + 4*CW1_N;                   // 4*CW2_N floats
    short* Apk1 = (short*)(cw2 + 4*CW2_N);        // 73728 shorts
    short* Apk2 = Apk1 + 73728;                   // 147456 shorts
    short* h1pad = Apk2 + 147456;                 // 16*134*262*64 shorts
    short* xpad  = h1pad + (size_t)16*H1_PLANE*64 + 4096;
    short* h2    = xpad;                          // xpad dead before conv2 writes h2

    prep_kernel<<<PREP_BLOCKS, 256, 0, stream>>>(a1h, a1w, a2h, a2w, w1, w2,
                                                 stats, cw1, cw2, Apk1, Apk2);
    {
        long n4 = ((size_t)16*H1_PLANE*64) * 2 / 16;
        zero_xpad_kernel<<<ZBLK + 16*132, 256, 0, stream>>>((uint4*)h1pad, n4, x, xpad);
    }

    // layer 1: in xpad [16][132][260][32] -> h1pad [16][134][262][64] (pad 2)
    lrlc_conv<32, 9><<<dim3(9, 33, 16), 256, 0, stream>>>(
        xpad, Apk1, cw1, b1, h1pad, sum1, sq1,
        /*Hin*/132, /*Win*/260, /*Hout*/130, /*Wout*/258,
        /*outW*/262, /*outPlane*/H1_PLANE, /*outPad*/2);
    finalize_kernel<<<1, 64, 0, stream>>>(sum1, sq1, g1, be1, A1, Bc1, (float)NPOS1);
    bnrelu_rows<<<16*130, 256, 0, stream>>>(h1pad, A1, Bc1);

    // layer 2: in h1pad -> h2 [16][132][260][64]
    lrlc_conv<64,18><<<dim3(9, 33, 16), 256, 0, stream>>>(
        h1pad, Apk2, cw2, b2, h2, sum2, sq2,
        /*Hin*/134, /*Win*/262, /*Hout*/132, /*Wout*/260,
        /*outW*/260, /*outPlane*/H2_PLANE, /*outPad*/0);
    finalize_kernel<<<1, 64, 0, stream>>>(sum2, sq2, g2, be2, A2, Bc2, (float)NPOS2);

    maxpool_rows<<<16*44, 256, 0, stream>>>(h2, A2, Bc2, out);
}

// Round 7
// 1165.654 us; speedup vs baseline: 1.0517x; 1.0517x over previous
//
#include <hip/hip_runtime.h>
#include <hip/hip_bf16.h>
#include <math.h>

#define COUT 64
#define EPS  1e-5f

typedef __hip_bfloat16 bf16;
typedef short  short8  __attribute__((ext_vector_type(8)));
typedef short  short4v __attribute__((ext_vector_type(4)));
typedef float  floatx4 __attribute__((ext_vector_type(4)));

__device__ __forceinline__ short bf16_bits(float f) {
    union { __hip_bfloat16 h; short s; } u;
    u.h = __float2bfloat16(f);
    return u.s;
}
__device__ __forceinline__ float bits_to_f32(short s) {
    union { __hip_bfloat16 h; short s; } u;
    u.s = s;
    return __bfloat162float(u.h);
}

// ---------------- geometry ----------------
#define H1_PLANE    (134*262)
#define H2_PLANE    (132*260)
#define NPOS1 (16*130*258)
#define NPOS2 (16*132*260)
#define CW1_N (130*258)     /* 33540 */
#define CW2_N (132*260)     /* 34320 */

#define CW1_BLK ((CW1_N + 255)/256)   /* 132 */
#define CW2_BLK ((CW2_N + 255)/256)   /* 135 */
#define PK1_BLK (9*1024/256)          /* 36 */
#define PK2_BLK (18*1024/256)         /* 72 */

// ---------------- fused prep: zero stats + cw1 + cw2 + pack1 + pack2 --------
__device__ __forceinline__ void cw_body(const float* __restrict__ ah, const float* __restrict__ aw,
                                        float* __restrict__ cw, int Lh, int Lw, int idx) {
    int n = Lh*Lw;
    if (idx >= n) return;
    int i = idx / Lw, j = idx - i*Lw;
    float v0 = ah[0*Lh+i] + aw[0*Lw+j];
    float v1 = ah[1*Lh+i] + aw[1*Lw+j];
    float v2 = ah[2*Lh+i] + aw[2*Lw+j];
    float v3 = ah[3*Lh+i] + aw[3*Lw+j];
    float m = fmaxf(fmaxf(v0,v1), fmaxf(v2,v3));
    v0 = __expf(v0-m); v1 = __expf(v1-m); v2 = __expf(v2-m); v3 = __expf(v3-m);
    float inv = 1.f/(v0+v1+v2+v3);
    cw[0*n+idx] = v0*inv; cw[1*n+idx] = v1*inv;
    cw[2*n+idx] = v2*inv; cw[3*n+idx] = v3*inv;
}

// Apk[((s*16+t)*64+l)*8+j] = A[m=t*16+(l&15)][k=s*32+(l>>4)*8+j], k=tap*CIN+ci
template<int CIN_, int NSLICES>
__device__ __forceinline__ void pack_body(const float* __restrict__ w, short* __restrict__ Apk, int gid) {
    if (gid >= NSLICES*1024) return;
    int l = gid & 63, t = (gid >> 6) & 15, s = gid >> 10;
    int m = t*16 + (l & 15);
    int r = m >> 6, co = m & 63;
    int kbase = s*32 + ((l >> 4) << 3);
    short8 v;
    #pragma unroll
    for (int j = 0; j < 8; ++j) {
        int k = kbase + j;
        int tap = k / CIN_, ci = k % CIN_;
        v[j] = bf16_bits(w[(((size_t)(r*COUT + co))*CIN_ + ci)*9 + tap]);
    }
    *reinterpret_cast<short8*>(Apk + (size_t)gid*8) = v;
}

__global__ void prep_kernel(const float* __restrict__ a1h, const float* __restrict__ a1w,
                            const float* __restrict__ a2h, const float* __restrict__ a2w,
                            const float* __restrict__ w1, const float* __restrict__ w2,
                            float* __restrict__ stats, float* __restrict__ cw1,
                            float* __restrict__ cw2, short* __restrict__ Apk1,
                            short* __restrict__ Apk2) {
    int bx = blockIdx.x;
    if (bx == 0) {
        stats[threadIdx.x] = 0.f; stats[threadIdx.x + 256] = 0.f;
    } else if (bx < 1 + CW1_BLK) {
        cw_body(a1h, a1w, cw1, 130, 258, (bx-1)*256 + threadIdx.x);
    } else if (bx < 1 + CW1_BLK + CW2_BLK) {
        cw_body(a2h, a2w, cw2, 132, 260, (bx-(1+CW1_BLK))*256 + threadIdx.x);
    } else if (bx < 1 + CW1_BLK + CW2_BLK + PK1_BLK) {
        pack_body<32, 9>(w1, Apk1, (bx-(1+CW1_BLK+CW2_BLK))*256 + threadIdx.x);
    } else {
        pack_body<64,18>(w2, Apk2, (bx-(1+CW1_BLK+CW2_BLK+PK1_BLK))*256 + threadIdx.x);
    }
}
#define PREP_BLOCKS (1 + CW1_BLK + CW2_BLK + PK1_BLK + PK2_BLK)  /* 376 */

// ---------------- fused: zero h1pad + build xpad -----------------------------
#define ZBLK 2048
__global__ void zero_xpad_kernel(uint4* __restrict__ h1p, long n4,
                                 const float* __restrict__ x, short* __restrict__ xp) {
    if (blockIdx.x < ZBLK) {
        for (long i = (long)blockIdx.x*256 + threadIdx.x; i < n4; i += (long)ZBLK*256)
            h1p[i] = make_uint4(0,0,0,0);
    } else {
        int row = blockIdx.x - ZBLK;          // b*132 + ih
        int b = row / 132, ih = row - b*132;
        int ci = threadIdx.x & 31, iw0 = threadIdx.x >> 5;
        for (int iw = iw0; iw < 260; iw += 8) {
            float v = 0.f;
            if (ih >= 2 && ih < 130 && iw >= 2 && iw < 258)
                v = x[(((size_t)b*32 + ci)*128 + (ih-2))*256 + (iw-2)];
            xp[((size_t)row*260 + iw)*32 + ci] = bf16_bits(v);
        }
    }
}

// ---------------- LDS-staged MFMA implicit-GEMM LRLC conv --------------------
// Block = 4 waves. Output tile: 4 rows x 32 cols (N=128), M=256 (4 rank x 64 co).
// Input patch 6 rows x 34 cols x CIN staged to LDS once; K-loop barrier-free.
// LDS layout padded: 16B-unit stride per column = GPC+1 (kills the 128B-stride
// same-bank pattern: bank step 4 (CIN64) / 20 (CIN32) -> 2-way aliasing = free).
template<int CIN_, int NSLICES>
__launch_bounds__(256, 2)
__global__ void lrlc_conv(const short* __restrict__ Bpl, const short* __restrict__ Apk,
                          const float* __restrict__ cw, const float* __restrict__ bias,
                          short* __restrict__ Out, float* __restrict__ sum, float* __restrict__ sq,
                          int Hin, int Win, int Hout, int Wout,
                          int outW, int outPlane, int outPad) {
    constexpr int GSH = (CIN_ == 64) ? 3 : 2;      // 16B groups per col = CIN_/8
    constexpr int GPC = 1 << GSH;
    constexpr int PSTR = GPC + 1;                  // padded col stride (16B units)
    constexpr int TILE_SLOTS = 6*34*GPC;
    __shared__ short tile[6*34*PSTR*8];
    __shared__ float cwS[512];

    const int tid  = threadIdx.x;
    const int w    = tid >> 6, l = tid & 63;
    const int quad = l >> 4, l15 = l & 15;
    const int b    = blockIdx.z;
    const int ow0  = blockIdx.x * 32;
    const int oh0  = blockIdx.y * 4;

    // combining weights for this tile (clamped; invalid n masked at store)
    for (int t = tid; t < 512; t += 256) {
        int r = t >> 7, n = t & 127;
        int oh = min(oh0 + (n >> 5), Hout-1);
        int ow = min(ow0 + (n & 31), Wout-1);
        cwS[t] = cw[((size_t)r*Hout + oh)*Wout + ow];
    }
    // stage input patch: rows oh0..oh0+5, cols ow0..ow0+33 (clamped)
    const short* Bb = Bpl + (size_t)b*Hin*Win*CIN_;
    for (int slot = tid; slot < TILE_SLOTS; slot += 256) {
        int g  = slot & (GPC-1); int cu = slot >> GSH;
        int rr = cu / 34, cc = cu - rr*34;
        int ih = min(oh0 + rr, Hin-1);
        int ic = min(ow0 + cc, Win-1);
        *reinterpret_cast<short8*>(&tile[(cu*PSTR + g)*8]) =
            *reinterpret_cast<const short8*>(Bb + ((size_t)ih*Win + ic)*CIN_ + g*8);
    }
    __syncthreads();

    // per-j LDS base (position part, padded units); tap/group add per-slice consts
    int base0[8];
    #pragma unroll
    for (int j = 0; j < 8; ++j) {
        int n = j*16 + l15;
        base0[j] = ((n >> 5)*34 + (n & 31))*PSTR + quad;
    }

    floatx4 acc[4][8];
    #pragma unroll
    for (int i = 0; i < 4; ++i)
        #pragma unroll
        for (int j = 0; j < 8; ++j)
            acc[i][j] = (floatx4){0.f,0.f,0.f,0.f};

    #pragma unroll 2
    for (int s = 0; s < NSLICES; ++s) {
        const int tap = (CIN_ == 32) ? s : (s >> 1);
        const int gx  = (CIN_ == 32) ? 0 : ((s & 1) << 2);
        const int koff = ((tap/3)*34 + (tap%3))*PSTR + gx;
        short8 bfr[8];
        #pragma unroll
        for (int j = 0; j < 8; ++j)
            bfr[j] = *reinterpret_cast<const short8*>(&tile[(base0[j] + koff)*8]);
        #pragma unroll
        for (int i = 0; i < 4; ++i) {
            short8 afr = *reinterpret_cast<const short8*>(
                Apk + (size_t)s*8192 + i*2048 + w*512 + l*8);
            #pragma unroll
            for (int j = 0; j < 8; ++j)
                acc[i][j] = __builtin_amdgcn_mfma_f32_16x16x32_bf16(afr, bfr[j], acc[i][j], 0, 0, 0);
        }
    }

    // epilogue: rank-combine, +bias, store bf16x4, fused BN stats (fp32)
    const int co_base = w*16 + quad*4;
    float bs[4];
    #pragma unroll
    for (int rg = 0; rg < 4; ++rg) bs[rg] = bias[co_base + rg];
    float st[4] = {0.f,0.f,0.f,0.f}, st2[4] = {0.f,0.f,0.f,0.f};
    #pragma unroll
    for (int j = 0; j < 8; ++j) {
        int n  = j*16 + l15;
        int oh = oh0 + (n >> 5), ow = ow0 + (n & 31);
        bool valid = (oh < Hout) && (ow < Wout);
        float c0 = cwS[n], c1 = cwS[128+n], c2 = cwS[256+n], c3 = cwS[384+n];
        short4v pk;
        #pragma unroll
        for (int rg = 0; rg < 4; ++rg) {
            float v = acc[0][j][rg]*c0 + acc[1][j][rg]*c1
                    + acc[2][j][rg]*c2 + acc[3][j][rg]*c3 + bs[rg];
            if (valid) { st[rg] += v; st2[rg] = fmaf(v, v, st2[rg]); }
            pk[rg] = bf16_bits(v);
        }
        if (valid) {
            size_t op = ((size_t)b*outPlane + (size_t)(oh + outPad)*outW + (ow + outPad))*(size_t)COUT + co_base;
            *reinterpret_cast<short4v*>(Out + op) = pk;
        }
    }
    #pragma unroll
    for (int m = 1; m < 16; m <<= 1) {
        #pragma unroll
        for (int rg = 0; rg < 4; ++rg) {
            st[rg]  += __shfl_xor(st[rg],  m, 16);
            st2[rg] += __shfl_xor(st2[rg], m, 16);
        }
    }
    if (l15 == 0) {
        #pragma unroll
        for (int rg = 0; rg < 4; ++rg) {
            atomicAdd(&sum[co_base+rg], st[rg]);
            atomicAdd(&sq[co_base+rg],  st2[rg]);
        }
    }
}

__global__ void finalize_kernel(const float* __restrict__ sum, const float* __restrict__ sumsq,
                                const float* __restrict__ g, const float* __restrict__ be,
                                float* __restrict__ A, float* __restrict__ Bc, float cnt) {
    int c = threadIdx.x;
    if (c >= COUT) return;
    float mean = sum[c]/cnt;
    float var  = sumsq[c]/cnt - mean*mean;
    float inv  = rsqrtf(var + EPS);
    float a = g[c]*inv;
    A[c]  = a;
    Bc[c] = fmaf(-mean, a, be[c]);
}

// row-based in-place BN+ReLU on h1pad interior; grid 16*130, block 256
__global__ void bnrelu_rows(short* __restrict__ h, const float* __restrict__ A,
                            const float* __restrict__ Bc) {
    __shared__ float sA[64], sB[64];
    if (threadIdx.x < 64) { sA[threadIdx.x] = A[threadIdx.x]; sB[threadIdx.x] = Bc[threadIdx.x]; }
    __syncthreads();
    int row = blockIdx.x;                 // b*130 + oh
    int b = row / 130, oh = row - b*130;
    short* base = h + ((size_t)(b*134 + oh + 2)*262 + 2)*64;
    const int nvec = 258*64/8;            // 2064
    for (int it = threadIdx.x; it < nvec; it += 256) {
        short8 d = *reinterpret_cast<short8*>(base + it*8);
        int c0 = (it*8) & 63;
        #pragma unroll
        for (int q = 0; q < 8; ++q) {
            float v = bits_to_f32(d[q]);
            int c = c0 + q;
            v = fmaxf(fmaf(v, sA[c], sB[c]), 0.f);
            d[q] = bf16_bits(v);
        }
        *reinterpret_cast<short8*>(base + it*8) = d;
    }
}

// fused BN2+ReLU+3x3/3 maxpool: h2 NHWC -> out fp32 NCHW [16,64,44,86]
__global__ void maxpool_rows(const short* __restrict__ h2, const float* __restrict__ A,
                             const float* __restrict__ Bc, float* __restrict__ out) {
    __shared__ float sA[64], sB[64];
    if (threadIdx.x < 64) { sA[threadIdx.x] = A[threadIdx.x]; sB[threadIdx.x] = Bc[threadIdx.x]; }
    __syncthreads();
    int row = blockIdx.x;                 // b*44 + ph
    int b = row / 44, ph = row - b*44;
    for (int item = threadIdx.x; item < 86*16; item += 256) {
        int cg = item & 15, pw = item >> 4;
        float m[4] = {0.f,0.f,0.f,0.f};
        #pragma unroll
        for (int i = 0; i < 3; ++i) {
            const short* rp = h2 + ((size_t)(b*132 + ph*3 + i)*260 + pw*3)*64 + cg*4;
            #pragma unroll
            for (int j = 0; j < 3; ++j) {
                short4v d = *reinterpret_cast<const short4v*>(rp + j*64);
                #pragma unroll
                for (int q = 0; q < 4; ++q) {
                    int c = cg*4 + q;
                    float v = fmaf(bits_to_f32(d[q]), sA[c], sB[c]);
                    m[q] = fmaxf(m[q], v);
                }
            }
        }
        #pragma unroll
        for (int q = 0; q < 4; ++q)
            out[((size_t)(b*64 + cg*4 + q)*44 + ph)*86 + pw] = m[q];
    }
}

extern "C" void kernel_launch(void* const* d_in, const int* in_sizes, int n_in,
                              void* d_out, int out_size, void* d_ws, size_t ws_size,
                              hipStream_t stream) {
    const float* x   = (const float*)d_in[0];
    const float* w1  = (const float*)d_in[1];
    const float* b1  = (const float*)d_in[2];
    const float* a1h = (const float*)d_in[3];
    const float* a1w = (const float*)d_in[4];
    const float* g1  = (const float*)d_in[5];
    const float* be1 = (const float*)d_in[6];
    const float* w2  = (const float*)d_in[7];
    const float* b2  = (const float*)d_in[8];
    const float* a2h = (const float*)d_in[9];
    const float* a2w = (const float*)d_in[10];
    const float* g2  = (const float*)d_in[11];
    const float* be2 = (const float*)d_in[12];
    float* out = (float*)d_out;

    char* ws = (char*)d_ws;
    float* stats = (float*)ws;                    // 512 floats
    float* sum1 = stats;       float* sq1 = stats + 64;
    float* A1   = stats + 128; float* Bc1 = stats + 192;
    float* sum2 = stats + 256; float* sq2 = stats + 320;
    float* A2   = stats + 384; float* Bc2 = stats + 448;
    float* cw1 = (float*)(ws + 2048);             // 4*CW1_N floats
    float* cw2 = cw1 + 4*CW1_N;                   // 4*CW2_N floats
    short* Apk1 = (short*)(cw2 + 4*CW2_N);        // 73728 shorts
    short* Apk2 = Apk1 + 73728;                   // 147456 shorts
    short* h1pad = Apk2 + 147456;                 // 16*134*262*64 shorts
    short* xpad  = h1pad + (size_t)16*H1_PLANE*64 + 4096;
    short* h2    = xpad;                          // xpad dead before conv2 writes h2

    prep_kernel<<<PREP_BLOCKS, 256, 0, stream>>>(a1h, a1w, a2h, a2w, w1, w2,
                                                 stats, cw1, cw2, Apk1, Apk2);
    {
        long n4 = ((size_t)16*H1_PLANE*64) * 2 / 16;
        zero_xpad_kernel<<<ZBLK + 16*132, 256, 0, stream>>>((uint4*)h1pad, n4, x, xpad);
    }

    // layer 1: in xpad [16][132][260][32] -> h1pad [16][134][262][64] (pad 2)
    lrlc_conv<32, 9><<<dim3(9, 33, 16), 256, 0, stream>>>(
        xpad, Apk1, cw1, b1, h1pad, sum1, sq1,
        /*Hin*/132, /*Win*/260, /*Hout*/130, /*Wout*/258,
        /*outW*/262, /*outPlane*/H1_PLANE, /*outPad*/2);
    finalize_kernel<<<1, 64, 0, stream>>>(sum1, sq1, g1, be1, A1, Bc1, (float)NPOS1);
    bnrelu_rows<<<16*130, 256, 0, stream>>>(h1pad, A1, Bc1);

    // layer 2: in h1pad -> h2 [16][132][260][64]
    lrlc_conv<64,18><<<dim3(9, 33, 16), 256, 0, stream>>>(
        h1pad, Apk2, cw2, b2, h2, sum2, sq2,
        /*Hin*/134, /*Win*/262, /*Hout*/132, /*Wout*/260,
        /*outW*/260, /*outPlane*/H2_PLANE, /*outPad*/0);
    finalize_kernel<<<1, 64, 0, stream>>>(sum2, sq2, g2, be2, A2, Bc2, (float)NPOS2);

    maxpool_rows<<<16*44, 256, 0, stream>>>(h2, A2, Bc2, out);
}